// Round 12
// baseline (477.865 us; speedup 1.0000x reference)
//
#include <hip/hip_runtime.h>
#include <cstdint>
#include <cstddef>

typedef __bf16 bf16x8 __attribute__((ext_vector_type(8)));
typedef __bf16 bf16x4 __attribute__((ext_vector_type(4)));
typedef float f32x4 __attribute__((ext_vector_type(4)));

__device__ __forceinline__ uint16_t f2bf(float f) {
    union { float f; uint32_t u; } v; v.f = f;
    uint32_t r = (v.u + 0x7fffu + ((v.u >> 16) & 1u)) >> 16;
    return (uint16_t)r;
}
__device__ __forceinline__ float bf2f(uint16_t h) {
    union { uint32_t u; float f; } v; v.u = ((uint32_t)h) << 16;
    return v.f;
}

// async 16B/lane global->LDS (wave-uniform LDS base; HW scatters lane i at +16i)
__device__ __forceinline__ void gload_lds16(const void* g, void* l) {
    __builtin_amdgcn_global_load_lds(
        (__attribute__((address_space(1))) void*)g,
        (__attribute__((address_space(3))) void*)l, 16, 0, 0);
}

// ---------------------------------------------------------------------------
// hidden fp32 -> bf16
// ---------------------------------------------------------------------------
__global__ __launch_bounds__(256) void k_tobf16(const float* __restrict__ X,
                                                uint16_t* __restrict__ Y) {
    int i = (blockIdx.x * 256 + threadIdx.x) * 4;
    f32x4 v = *reinterpret_cast<const f32x4*>(X + i);
    uint2 o;
    o.x = (uint32_t)f2bf(v[0]) | ((uint32_t)f2bf(v[1]) << 16);
    o.y = (uint32_t)f2bf(v[2]) | ((uint32_t)f2bf(v[3]) << 16);
    *reinterpret_cast<uint2*>(Y + i) = o;
}

// ---------------------------------------------------------------------------
// Weight transpose + convert: W (R x C, fp32) -> Wt (C x R, bf16)
// ---------------------------------------------------------------------------
__global__ __launch_bounds__(256) void k_transpose_w(const float* __restrict__ W,
                                                     uint16_t* __restrict__ Wt,
                                                     int R, int C) {
    __shared__ uint16_t tile[32][33];
    int c0 = blockIdx.x * 32;
    int r0 = blockIdx.y * 32;
    int t = threadIdx.x;
    int tc = t & 31, tr = t >> 5;
#pragma unroll
    for (int i = 0; i < 4; ++i) {
        int r = tr * 4 + i;
        tile[r][tc] = f2bf(W[(size_t)(r0 + r) * C + c0 + tc]);
    }
    __syncthreads();
#pragma unroll
    for (int i = 0; i < 4; ++i) {
        int c = tr * 4 + i;
        Wt[(size_t)(c0 + c) * R + r0 + tc] = tile[tc][c];
    }
}

// ---------------------------------------------------------------------------
// RoPE trig tables: CS/SN[s*64 + d]. Transcendentals ONLY here (r7 lesson:
// cosf/sinf inside the GEMM -> 64-VGPR call cap -> acc spills -> 10x).
// ---------------------------------------------------------------------------
__global__ __launch_bounds__(256) void k_trig(const int* __restrict__ pos_ids,
                                              float* __restrict__ CS,
                                              float* __restrict__ SN) {
    int idx = blockIdx.x * 256 + threadIdx.x;   // 131072
    int d = idx & 63;
    int s = idx >> 6;
    float pos = (float)pos_ids[s];
    float ang = pos * exp2f((float)d * (-19.931568569324174f / 64.0f));
    CS[idx] = cosf(ang);
    SN[idx] = sinf(ang);
}

// ---------------------------------------------------------------------------
// K repack: row-major roped K (2048x512) -> fragment-major Kf.
// One 16B load + one perfectly-coalesced 16B store per thread (4MB total).
// Mapping matches flash's consumer: Kf[kvh][(t*2+nt)*4+c][lane*8+e],
// lane = quad*16+l15, tok = t*32+nt*16+l15, d = c*32+quad*8+e.
// Bit decode (17 bits total): l15[0:3] quad[4:5] c[6:7] nt[8] t[9:14] kvh[15:16].
// r11 bug: t was decoded as 4 bits ((lin>>9)&15) -> tiles 16..63 corrupted
// (absmax 6.9). Fixed: t=(lin>>9)&63, kvh=lin>>15.
// ---------------------------------------------------------------------------
__global__ __launch_bounds__(256) void k_repack_k(const uint16_t* __restrict__ Kb,
                                                  uint16_t* __restrict__ Kf) {
    int lin = blockIdx.x * 256 + threadIdx.x;      // 131072
    int l15  = lin & 15;
    int quad = (lin >> 4) & 3;
    int c    = (lin >> 6) & 3;
    int nt   = (lin >> 8) & 1;
    int t    = (lin >> 9) & 63;
    int kvh  = lin >> 15;
    int tok = t * 32 + nt * 16 + l15;
    const uint16_t* src = Kb + (size_t)tok * 512 + kvh * 128 + c * 32 + quad * 8;
    uint16_t* dst = Kf + (size_t)kvh * 262144 +
                    ((size_t)(t * 2 + nt) * 4 + c) * 512 + quad * 128 + l15 * 8;
    *reinterpret_cast<uint4*>(dst) = *reinterpret_cast<const uint4*>(src);
}

// ---------------------------------------------------------------------------
// m97-style GEMM with FUSED RoPE (table-based). Q and K write row-major
// (coalesced rope stores -- r10 showed frag-major K scatter here costs
// +40us); V writes fragment-major directly (its packed 8B stores are 128B-
// contiguous per quad, verified coalesced). K is repacked by k_repack_k.
// Wave column remap: wave owns cols {wn2+0..31, wn2+64..95} so rope pairs
// (d, d+64) are (j, j+2) within the wave. Q scaled by 1/sqrt(128)*log2e.
// T1 XCD swizzle kept. 2-barrier K-loop kept (m99/m100: dbuf regresses).
// ---------------------------------------------------------------------------
#define BK 32

__global__ __launch_bounds__(256) void k_gemm_qkv(
    const uint16_t* __restrict__ A,
    const uint16_t* __restrict__ WqT,
    const uint16_t* __restrict__ WkT,
    const uint16_t* __restrict__ WvT,
    const float* __restrict__ CS,
    const float* __restrict__ SN,
    uint16_t* __restrict__ Q,
    uint16_t* __restrict__ Kb,
    uint16_t* __restrict__ Vf)
{
    __shared__ uint16_t Als[128 * BK];
    __shared__ uint16_t Bls[128 * BK];

    int bid = blockIdx.x + blockIdx.y * 36;          // 0..575
    int rid = (bid & 7) * 72 + (bid >> 3);           // XCD-chunked remap
    int nt = rid % 36;
    int m0 = (rid / 36) * 128;

    const uint16_t* Bt;
    if (nt < 28)      Bt = WqT + (size_t)nt * 128 * 3584;
    else if (nt < 32) Bt = WkT + (size_t)(nt - 28) * 128 * 3584;
    else              Bt = WvT + (size_t)(nt - 32) * 128 * 3584;

    int tid = threadIdx.x;
    int w = tid >> 6, lane = tid & 63, quad = lane >> 4, l15 = lane & 15;
    int wm = (w >> 1) * 64;
    int wn2 = (w & 1) * 32;            // column remap base

    int lrow = lane >> 2;
    int lcol = (lane & 3) * 8;

    const uint16_t* aS = A  + (size_t)(m0 + w * 32 + lrow) * 3584 + lcol;
    const uint16_t* bS = Bt + (size_t)(w * 32 + lrow) * 3584 + lcol;
    uint16_t* aD0 = &Als[(w * 32) * BK];
    uint16_t* aD1 = &Als[(w * 32 + 16) * BK];
    uint16_t* bD0 = &Bls[(w * 32) * BK];
    uint16_t* bD1 = &Bls[(w * 32 + 16) * BK];

    f32x4 acc[4][4] = {};

    for (int k0 = 0; k0 < 3584; k0 += BK) {
        __syncthreads();
        gload_lds16(aS + k0, aD0);
        gload_lds16(aS + k0 + (size_t)16 * 3584, aD1);
        gload_lds16(bS + k0, bD0);
        gload_lds16(bS + k0 + (size_t)16 * 3584, bD1);
        __syncthreads();

        bf16x8 af[4], bfr[4];
#pragma unroll
        for (int i = 0; i < 4; ++i)
            af[i] = *reinterpret_cast<const bf16x8*>(&Als[(wm + i * 16 + l15) * BK + quad * 8]);
#pragma unroll
        for (int j = 0; j < 4; ++j) {
            int br = wn2 + (j & 1) * 16 + (j >> 1) * 64;   // remapped column group
            bfr[j] = *reinterpret_cast<const bf16x8*>(&Bls[(br + l15) * BK + quad * 8]);
        }
#pragma unroll
        for (int i = 0; i < 4; ++i)
#pragma unroll
            for (int j = 0; j < 4; ++j)
                acc[i][j] = __builtin_amdgcn_mfma_f32_16x16x32_bf16(af[i], bfr[j], acc[i][j], 0, 0, 0);
    }

    if (nt < 28) {
        // -------- Q with fused RoPE (cs/sn from L2-resident tables) --------
        int colBase = nt * 128;
        const float osc = 0.08838834764831845f * 1.4426950408889634f;
#pragma unroll
        for (int i = 0; i < 4; ++i)
#pragma unroll
            for (int r = 0; r < 4; ++r) {
                int grow = m0 + wm + i * 16 + quad * 4 + r;
                const float* csr = CS + (size_t)grow * 64;
                const float* snr = SN + (size_t)grow * 64;
#pragma unroll
                for (int jp = 0; jp < 2; ++jp) {
                    int d64 = wn2 + jp * 16 + l15;
                    float cs = csr[d64];
                    float sn = snr[d64];
                    float x1 = acc[i][jp][r];              // col d64
                    float x2 = acc[i][jp + 2][r];          // col d64+64
                    Q[(size_t)grow * 3584 + colBase + d64]      = f2bf((x1 * cs - x2 * sn) * osc);
                    Q[(size_t)grow * 3584 + colBase + d64 + 64] = f2bf((x2 * cs + x1 * sn) * osc);
                }
            }
    } else if (nt < 32) {
        // -------- K with fused RoPE: row-major coalesced (repacked later) --
        int colBase = (nt - 28) * 128;
#pragma unroll
        for (int i = 0; i < 4; ++i)
#pragma unroll
            for (int r = 0; r < 4; ++r) {
                int grow = m0 + wm + i * 16 + quad * 4 + r;
                const float* csr = CS + (size_t)grow * 64;
                const float* snr = SN + (size_t)grow * 64;
#pragma unroll
                for (int jp = 0; jp < 2; ++jp) {
                    int d64 = wn2 + jp * 16 + l15;
                    float cs = csr[d64];
                    float sn = snr[d64];
                    float x1 = acc[i][jp][r];
                    float x2 = acc[i][jp + 2][r];
                    Kb[(size_t)grow * 512 + colBase + d64]      = f2bf(x1 * cs - x2 * sn);
                    Kb[(size_t)grow * 512 + colBase + d64 + 64] = f2bf(x2 * cs + x1 * sn);
                }
            }
    } else {
        // -------- V: fragment-major, packed 8B (coalesced per quad) --------
        // V_frag elem = kvh*262144 + (t*8+dt)*512 + quad''*128 + l15''*8 + e
        // t=tok>>5, quad''=(tok>>3)&3, e=tok&7, dt=d>>4, l15''=d&15
        uint16_t* Vfh = Vf + (size_t)(nt - 32) * 262144;
#pragma unroll
        for (int i = 0; i < 4; ++i) {
            int tok0 = m0 + wm + i * 16 + quad * 4;
            size_t tb = (size_t)((tok0 >> 5)) * 8 * 512 + (size_t)((tok0 >> 3) & 3) * 128 + (tok0 & 7);
#pragma unroll
            for (int j = 0; j < 4; ++j) {
                int c = wn2 + (j & 1) * 16 + (j >> 1) * 64 + l15;
                bf16x4 pk;
#pragma unroll
                for (int r = 0; r < 4; ++r) pk[r] = (__bf16)acc[i][j][r];
                *reinterpret_cast<bf16x4*>(&Vfh[tb + (size_t)(c >> 4) * 512 + (size_t)(c & 15) * 8]) = pk;
            }
        }
    }
}

__global__ __launch_bounds__(256) void k_gemm_o(
    const uint16_t* __restrict__ A,
    const uint16_t* __restrict__ WoT,
    float* __restrict__ out)
{
    __shared__ uint16_t Als[128 * BK];
    __shared__ uint16_t Bls[128 * BK];

    int bid = blockIdx.x + blockIdx.y * 28;          // 0..447
    int rid = (bid & 7) * 56 + (bid >> 3);           // XCD-chunked remap
    int nt = rid % 28;
    int m0 = (rid / 28) * 128;
    const uint16_t* Bt = WoT + (size_t)nt * 128 * 3584;

    int tid = threadIdx.x;
    int w = tid >> 6, lane = tid & 63, quad = lane >> 4, l15 = lane & 15;
    int wm = (w >> 1) * 64, wn = (w & 1) * 64;

    int lrow = lane >> 2;
    int lcol = (lane & 3) * 8;

    const uint16_t* aS = A  + (size_t)(m0 + w * 32 + lrow) * 3584 + lcol;
    const uint16_t* bS = Bt + (size_t)(w * 32 + lrow) * 3584 + lcol;
    uint16_t* aD0 = &Als[(w * 32) * BK];
    uint16_t* aD1 = &Als[(w * 32 + 16) * BK];
    uint16_t* bD0 = &Bls[(w * 32) * BK];
    uint16_t* bD1 = &Bls[(w * 32 + 16) * BK];

    f32x4 acc[4][4] = {};

    for (int k0 = 0; k0 < 3584; k0 += BK) {
        __syncthreads();
        gload_lds16(aS + k0, aD0);
        gload_lds16(aS + k0 + (size_t)16 * 3584, aD1);
        gload_lds16(bS + k0, bD0);
        gload_lds16(bS + k0 + (size_t)16 * 3584, bD1);
        __syncthreads();

        bf16x8 af[4], bfr[4];
#pragma unroll
        for (int i = 0; i < 4; ++i)
            af[i] = *reinterpret_cast<const bf16x8*>(&Als[(wm + i * 16 + l15) * BK + quad * 8]);
#pragma unroll
        for (int j = 0; j < 4; ++j)
            bfr[j] = *reinterpret_cast<const bf16x8*>(&Bls[(wn + j * 16 + l15) * BK + quad * 8]);
#pragma unroll
        for (int i = 0; i < 4; ++i)
#pragma unroll
            for (int j = 0; j < 4; ++j)
                acc[i][j] = __builtin_amdgcn_mfma_f32_16x16x32_bf16(af[i], bfr[j], acc[i][j], 0, 0, 0);
    }

#pragma unroll
    for (int i = 0; i < 4; ++i)
#pragma unroll
        for (int r = 0; r < 4; ++r) {
            int grow = m0 + wm + i * 16 + quad * 4 + r;
#pragma unroll
            for (int j = 0; j < 4; ++j) {
                int gcol = nt * 128 + wn + j * 16 + l15;
                out[(size_t)grow * 3584 + gcol] = acc[i][j][r];
            }
        }
}

// ---------------------------------------------------------------------------
// Flash attention, split-K within block, swapped QK^T. K/V read from
// fragment-major layouts: every fragment load = uniform_base + lane*16B
// (coalesced 4 lines/instr vs 16-line gather -- confirmed ~-35us in r10).
// Block = 4 waves over the SAME 32 q rows; wave w owns key-tiles {w, w+4,..}.
// No barriers in main loop; bf16 AccS staging + per-wave weighted combine.
// T13 defer-rescale.
// ---------------------------------------------------------------------------
#define FPLD 40

__global__ __launch_bounds__(256, 2) void k_flash(
    const uint16_t* __restrict__ Q,    // 2048x3584 (roped, *1/sqrt(d)*log2e)
    const uint16_t* __restrict__ Kf,   // frag-major, 4 x 262144
    const uint16_t* __restrict__ Vf,   // frag-major, 4 x 262144
    uint16_t* __restrict__ O)          // 2048x3584
{
    __shared__ uint16_t Pls[4][32 * FPLD];
    __shared__ uint16_t AccS[4][32 * 128];
    __shared__ float    Ml[4][32][2];

    int h  = blockIdx.x;               // 0..27
    int qb = 63 - (int)blockIdx.y;     // heavy first
    int kvh = h / 7;
    int tid = threadIdx.x;
    int w = tid >> 6, lane = tid & 63, quad = lane >> 4, l15 = lane & 15;
    int q0 = qb * 32;

    const uint16_t* Kfh = Kf + (size_t)kvh * 262144;
    const uint16_t* Vfh = Vf + (size_t)kvh * 262144;
    int lo8 = lane * 8;
    __bf16* Pw = reinterpret_cast<__bf16*>(&Pls[w][0]);

    // Q fragments: 32 rows (2 x 16). B-operand of the swapped mfma.
    bf16x8 qf[2][4];
#pragma unroll
    for (int s = 0; s < 2; ++s) {
        const uint16_t* qp = Q + (size_t)(q0 + s * 16 + l15) * 3584 + h * 128 + quad * 8;
#pragma unroll
        for (int c = 0; c < 4; ++c)
            qf[s][c] = *reinterpret_cast<const bf16x8*>(qp + c * 32);
    }

    f32x4 acc[2][8] = {};
    float m_i[2], l_i[2];
    m_i[0] = m_i[1] = -1e30f;
    l_i[0] = l_i[1] = 0.f;

    int tmax = qb;                     // tiles 0..qb (32 keys each)
    bf16x8 kf[8];
    int t = w;
    if (t <= tmax) {                   // prefetch first owned K tile (coalesced)
#pragma unroll
        for (int nt = 0; nt < 2; ++nt)
#pragma unroll
            for (int c = 0; c < 4; ++c)
                kf[nt * 4 + c] = *reinterpret_cast<const bf16x8*>(
                    Kfh + ((size_t)(t * 2 + nt) * 4 + c) * 512 + lo8);
    }

    for (; t <= tmax; t += 4) {
        int kb = t * 32;
        // V frags issued now, consumed after softmax (coalesced)
        bf16x8 vf[8];
#pragma unroll
        for (int dt = 0; dt < 8; ++dt)
            vf[dt] = *reinterpret_cast<const bf16x8*>(
                Vfh + ((size_t)t * 8 + dt) * 512 + lo8);

        // QK^T swapped: sc[s][nt][r] = S[key=kb+nt*16+quad*4+r][q=q0+s*16+l15]
        f32x4 sc[2][2] = {};
#pragma unroll
        for (int nt = 0; nt < 2; ++nt)
#pragma unroll
            for (int c = 0; c < 4; ++c) {
                sc[0][nt] = __builtin_amdgcn_mfma_f32_16x16x32_bf16(kf[nt * 4 + c], qf[0][c], sc[0][nt], 0, 0, 0);
                sc[1][nt] = __builtin_amdgcn_mfma_f32_16x16x32_bf16(kf[nt * 4 + c], qf[1][c], sc[1][nt], 0, 0, 0);
            }

        // prefetch next owned K tile (hidden under softmax + PV)
        int tn = t + 4;
        if (tn <= tmax) {
#pragma unroll
            for (int nt = 0; nt < 2; ++nt)
#pragma unroll
                for (int c = 0; c < 4; ++c)
                    kf[nt * 4 + c] = *reinterpret_cast<const bf16x8*>(
                        Kfh + ((size_t)(tn * 2 + nt) * 4 + c) * 512 + lo8);
        }

        // causal mask (only possible on the last tile: kb+31 > q0)
        if (kb + 31 > q0) {
#pragma unroll
            for (int s = 0; s < 2; ++s) {
                int row = q0 + s * 16 + l15;
#pragma unroll
                for (int nt = 0; nt < 2; ++nt) {
                    int keyb = kb + nt * 16 + quad * 4;
#pragma unroll
                    for (int r = 0; r < 4; ++r)
                        if (keyb + r > row) sc[s][nt][r] = -1e30f;
                }
            }
        }

        // online softmax: lane owns one q-row per s
#pragma unroll
        for (int s = 0; s < 2; ++s) {
            float mx = fmaxf(fmaxf(fmaxf(sc[s][0][0], sc[s][0][1]), fmaxf(sc[s][0][2], sc[s][0][3])),
                             fmaxf(fmaxf(sc[s][1][0], sc[s][1][1]), fmaxf(sc[s][1][2], sc[s][1][3])));
            mx = fmaxf(mx, __shfl_xor(mx, 16));
            mx = fmaxf(mx, __shfl_xor(mx, 32));
            bool nd = mx > m_i[s] + 11.5f;       // T13 defer-rescale
            float mn = nd ? mx : m_i[s];
            float alf = __builtin_amdgcn_exp2f(m_i[s] - mn);
            m_i[s] = mn;

            float rs = 0.f;
#pragma unroll
            for (int nt = 0; nt < 2; ++nt)
#pragma unroll
                for (int r = 0; r < 4; ++r) {
                    float p = __builtin_amdgcn_exp2f(sc[s][nt][r] - mn);
                    sc[s][nt][r] = p;
                    rs += p;
                }
            rs += __shfl_xor(rs, 16);
            rs += __shfl_xor(rs, 32);
            l_i[s] = l_i[s] * alf + rs;

            if (__any(nd)) {           // rare: rescale acc rows (q=quad*4+r)
                f32x4 alfr;
#pragma unroll
                for (int r = 0; r < 4; ++r)
                    alfr[r] = __shfl(alf, quad * 4 + r);
#pragma unroll
                for (int dt = 0; dt < 8; ++dt)
                    acc[s][dt] *= alfr;
            }

            // packed P-store: row q=s*16+l15, keys nt*16+quad*4..+3 (8B each)
#pragma unroll
            for (int nt = 0; nt < 2; ++nt) {
                bf16x4 pk;
#pragma unroll
                for (int r = 0; r < 4; ++r) pk[r] = (__bf16)sc[s][nt][r];
                *reinterpret_cast<bf16x4*>(&Pw[(s * 16 + l15) * FPLD + nt * 16 + quad * 4]) = pk;
            }
        }

        // PV: 32 q x 128 d over 32 keys (wave-private LDS, in-wave ordering)
        bf16x8 pf0 = *reinterpret_cast<const bf16x8*>(&Pw[l15 * FPLD + quad * 8]);
        bf16x8 pf1 = *reinterpret_cast<const bf16x8*>(&Pw[(16 + l15) * FPLD + quad * 8]);
#pragma unroll
        for (int dt = 0; dt < 8; ++dt) {
            acc[0][dt] = __builtin_amdgcn_mfma_f32_16x16x32_bf16(pf0, vf[dt], acc[0][dt], 0, 0, 0);
            acc[1][dt] = __builtin_amdgcn_mfma_f32_16x16x32_bf16(pf1, vf[dt], acc[1][dt], 0, 0, 0);
        }
    }

    // ---- write partials and combine across the 4 waves ----
    {
        __bf16* As = reinterpret_cast<__bf16*>(&AccS[w][0]);
#pragma unroll
        for (int s = 0; s < 2; ++s)
#pragma unroll
            for (int dt = 0; dt < 8; ++dt)
#pragma unroll
                for (int r = 0; r < 4; ++r)
                    As[(s * 16 + quad * 4 + r) * 128 + dt * 16 + l15] = (__bf16)acc[s][dt][r];
    }
    if (lane < 16) {                   // quad 0 lanes hold full stats for q=l15
        Ml[w][lane][0]      = m_i[0];
        Ml[w][lane][1]      = l_i[0];
        Ml[w][16 + lane][0] = m_i[1];
        Ml[w][16 + lane][1] = l_i[1];
    }
    __syncthreads();

    // combine: wave w handles rows w*8..w*8+7; lane -> (row, 16-col chunk)
    {
        int rowl = w * 8 + (lane >> 3);
        int c16 = (lane & 7) * 16;
        float m0 = Ml[0][rowl][0], m1 = Ml[1][rowl][0], m2 = Ml[2][rowl][0], m3 = Ml[3][rowl][0];
        float M = fmaxf(fmaxf(m0, m1), fmaxf(m2, m3));
        float s0 = __builtin_amdgcn_exp2f(m0 - M);
        float s1 = __builtin_amdgcn_exp2f(m1 - M);
        float s2 = __builtin_amdgcn_exp2f(m2 - M);
        float s3 = __builtin_amdgcn_exp2f(m3 - M);
        float lt = Ml[0][rowl][1] * s0 + Ml[1][rowl][1] * s1 +
                   Ml[2][rowl][1] * s2 + Ml[3][rowl][1] * s3;
        float inv = __builtin_amdgcn_rcpf(lt);
        float sw[4] = {s0, s1, s2, s3};

        float o[16];
#pragma unroll
        for (int j = 0; j < 16; ++j) o[j] = 0.f;
#pragma unroll
        for (int sl = 0; sl < 4; ++sl) {
            const uint16_t* src = &AccS[sl][rowl * 128 + c16];
            float ssc = sw[sl];
#pragma unroll
            for (int j = 0; j < 16; ++j)
                o[j] += bf2f(src[j]) * ssc;
        }
        uint16_t ob[16];
#pragma unroll
        for (int j = 0; j < 16; ++j) ob[j] = f2bf(o[j] * inv);
        uint16_t* op = O + (size_t)(q0 + rowl) * 3584 + h * 128 + c16;
        *reinterpret_cast<uint4*>(op)     = *reinterpret_cast<uint4*>(&ob[0]);
        *reinterpret_cast<uint4*>(op + 8) = *reinterpret_cast<uint4*>(&ob[8]);
    }
}

// ---------------------------------------------------------------------------
extern "C" void kernel_launch(void* const* d_in, const int* in_sizes, int n_in,
                              void* d_out, int out_size, void* d_ws, size_t ws_size,
                              hipStream_t stream) {
    const float* hidden = (const float*)d_in[0];
    const int*   pos    = (const int*)d_in[1];
    const float* Wq     = (const float*)d_in[2];
    const float* Wk     = (const float*)d_in[3];
    const float* Wv     = (const float*)d_in[4];
    const float* Wo     = (const float*)d_in[5];
    float* out = (float*)d_out;

    char* ws = (char*)d_ws;
    size_t o = 0;
    uint16_t* WqT = (uint16_t*)(ws + o); o += (size_t)3584 * 3584 * 2;
    uint16_t* WkT = (uint16_t*)(ws + o); o += (size_t)512  * 3584 * 2;
    uint16_t* WvT = (uint16_t*)(ws + o); o += (size_t)512  * 3584 * 2;
    uint16_t* WoT = (uint16_t*)(ws + o); o += (size_t)3584 * 3584 * 2;
    uint16_t* Xb  = (uint16_t*)(ws + o); o += (size_t)2048 * 3584 * 2;  // aliased as At
    uint16_t* Qb  = (uint16_t*)(ws + o); o += (size_t)2048 * 3584 * 2;
    uint16_t* Kb  = (uint16_t*)(ws + o); o += (size_t)2048 * 512  * 2;  // row-major
    uint16_t* Kf  = (uint16_t*)(ws + o); o += (size_t)2048 * 512  * 2;  // frag-major
    uint16_t* Vf  = (uint16_t*)(ws + o); o += (size_t)2048 * 512  * 2;  // frag-major
    float*    CSt = (float*)(ws + o);    o += (size_t)2048 * 64 * 4;
    float*    SNt = (float*)(ws + o);    o += (size_t)2048 * 64 * 4;
    uint16_t* At  = Xb;

    k_tobf16<<<dim3(7168), 256, 0, stream>>>(hidden, Xb);
    k_transpose_w<<<dim3(112, 112), 256, 0, stream>>>(Wq, WqT, 3584, 3584);
    k_transpose_w<<<dim3(16, 112),  256, 0, stream>>>(Wk, WkT, 3584, 512);
    k_transpose_w<<<dim3(16, 112),  256, 0, stream>>>(Wv, WvT, 3584, 512);
    k_transpose_w<<<dim3(112, 112), 256, 0, stream>>>(Wo, WoT, 3584, 3584);
    k_trig<<<dim3(512), 256, 0, stream>>>(pos, CSt, SNt);

    // QKV GEMM: fused RoPE, row-major K (coalesced), frag-major V
    k_gemm_qkv<<<dim3(36, 16), 256, 0, stream>>>(Xb, WqT, WkT, WvT, CSt, SNt, Qb, Kb, Vf);
    k_repack_k<<<dim3(512), 256, 0, stream>>>(Kb, Kf);
    k_flash<<<dim3(28, 64), 256, 0, stream>>>(Qb, Kf, Vf, At);
    k_gemm_o<<<dim3(28, 16), 256, 0, stream>>>(At, WoT, out);
}

// Round 13
// 419.531 us; speedup vs baseline: 1.1390x; 1.1390x over previous
//
#include <hip/hip_runtime.h>
#include <cstdint>
#include <cstddef>

typedef __bf16 bf16x8 __attribute__((ext_vector_type(8)));
typedef __bf16 bf16x4 __attribute__((ext_vector_type(4)));
typedef float f32x4 __attribute__((ext_vector_type(4)));

__device__ __forceinline__ uint16_t f2bf(float f) {
    union { float f; uint32_t u; } v; v.f = f;
    uint32_t r = (v.u + 0x7fffu + ((v.u >> 16) & 1u)) >> 16;
    return (uint16_t)r;
}
__device__ __forceinline__ float bf2f(uint16_t h) {
    union { uint32_t u; float f; } v; v.u = ((uint32_t)h) << 16;
    return v.f;
}

// async 16B/lane global->LDS (wave-uniform LDS base; HW scatters lane i at +16i)
__device__ __forceinline__ void gload_lds16(const void* g, void* l) {
    __builtin_amdgcn_global_load_lds(
        (__attribute__((address_space(1))) void*)g,
        (__attribute__((address_space(3))) void*)l, 16, 0, 0);
}

// ---------------------------------------------------------------------------
// hidden fp32 -> bf16
// ---------------------------------------------------------------------------
__global__ __launch_bounds__(256) void k_tobf16(const float* __restrict__ X,
                                                uint16_t* __restrict__ Y) {
    int i = (blockIdx.x * 256 + threadIdx.x) * 4;
    f32x4 v = *reinterpret_cast<const f32x4*>(X + i);
    uint2 o;
    o.x = (uint32_t)f2bf(v[0]) | ((uint32_t)f2bf(v[1]) << 16);
    o.y = (uint32_t)f2bf(v[2]) | ((uint32_t)f2bf(v[3]) << 16);
    *reinterpret_cast<uint2*>(Y + i) = o;
}

// ---------------------------------------------------------------------------
// Weight transpose + convert: W (R x C, fp32) -> Wt (C x R, bf16)
// ---------------------------------------------------------------------------
__global__ __launch_bounds__(256) void k_transpose_w(const float* __restrict__ W,
                                                     uint16_t* __restrict__ Wt,
                                                     int R, int C) {
    __shared__ uint16_t tile[32][33];
    int c0 = blockIdx.x * 32;
    int r0 = blockIdx.y * 32;
    int t = threadIdx.x;
    int tc = t & 31, tr = t >> 5;
#pragma unroll
    for (int i = 0; i < 4; ++i) {
        int r = tr * 4 + i;
        tile[r][tc] = f2bf(W[(size_t)(r0 + r) * C + c0 + tc]);
    }
    __syncthreads();
#pragma unroll
    for (int i = 0; i < 4; ++i) {
        int c = tr * 4 + i;
        Wt[(size_t)(c0 + c) * R + r0 + tc] = tile[tc][c];
    }
}

// ---------------------------------------------------------------------------
// RoPE trig tables: CS/SN[s*64 + d]. Transcendentals ONLY here (r7 lesson:
// cosf/sinf inside the GEMM -> 64-VGPR call cap -> acc spills -> 10x).
// ---------------------------------------------------------------------------
__global__ __launch_bounds__(256) void k_trig(const int* __restrict__ pos_ids,
                                              float* __restrict__ CS,
                                              float* __restrict__ SN) {
    int idx = blockIdx.x * 256 + threadIdx.x;   // 131072
    int d = idx & 63;
    int s = idx >> 6;
    float pos = (float)pos_ids[s];
    float ang = pos * exp2f((float)d * (-19.931568569324174f / 64.0f));
    CS[idx] = cosf(ang);
    SN[idx] = sinf(ang);
}

// ---------------------------------------------------------------------------
// K repack: row-major roped K (2048x512) -> fragment-major Kf.
// Verified correct in r12. ~4MB moved, ~4us.
// ---------------------------------------------------------------------------
__global__ __launch_bounds__(256) void k_repack_k(const uint16_t* __restrict__ Kb,
                                                  uint16_t* __restrict__ Kf) {
    int lin = blockIdx.x * 256 + threadIdx.x;      // 131072
    int l15  = lin & 15;
    int quad = (lin >> 4) & 3;
    int c    = (lin >> 6) & 3;
    int nt   = (lin >> 8) & 1;
    int t    = (lin >> 9) & 63;
    int kvh  = lin >> 15;
    int tok = t * 32 + nt * 16 + l15;
    const uint16_t* src = Kb + (size_t)tok * 512 + kvh * 128 + c * 32 + quad * 8;
    uint16_t* dst = Kf + (size_t)kvh * 262144 +
                    ((size_t)(t * 2 + nt) * 4 + c) * 512 + quad * 128 + l15 * 8;
    *reinterpret_cast<uint4*>(dst) = *reinterpret_cast<const uint4*>(src);
}

// ---------------------------------------------------------------------------
// V repack: d-major Vt (512 x 2048: index d_glob*2048 + tok) -> frag-major Vf.
// Vf elem = kvh*262144 + (t*8+dt)*512 + quad''*128 + l15''*8 + e, where
// tok = t*32 + quad''*8 + e, d = dt*16 + l15''  (matches r12's verified
// producer and flash's consumer). One 16B contiguous load (8 tokens) + one
// 16B store per thread. lin decode: oct[0:7] d[8:14] kvh[15:16].
// ---------------------------------------------------------------------------
__global__ __launch_bounds__(256) void k_repack_v(const uint16_t* __restrict__ Vt,
                                                  uint16_t* __restrict__ Vf) {
    int lin = blockIdx.x * 256 + threadIdx.x;      // 131072
    int oct = lin & 255;                           // tok0 = oct*8
    int d   = (lin >> 8) & 127;
    int kvh = lin >> 15;
    int t     = oct >> 2;
    int quad2 = oct & 3;
    int dt    = d >> 4;
    int l152  = d & 15;
    const uint16_t* src = Vt + ((size_t)kvh * 128 + d) * 2048 + (size_t)oct * 8;
    uint16_t* dst = Vf + (size_t)kvh * 262144 +
                    ((size_t)t * 8 + dt) * 512 + quad2 * 128 + l152 * 8;
    *reinterpret_cast<uint4*>(dst) = *reinterpret_cast<const uint4*>(src);
}

// ---------------------------------------------------------------------------
// m97-style GEMM with FUSED RoPE (table-based) — r8's epilogue RESTORED
// verbatim (unified Q/K branch + V -> Vt[d][s]); that configuration measured
// <124.5us, vs 160.5us for the r10/r12 3-way epilogue (A/B this round).
// Flash's frag-major layouts are produced by the repack kernels instead.
// Wave column remap: wave owns cols {wn2+0..31, wn2+64..95} so rope pairs
// (d, d+64) are (j, j+2) within the wave. Q scaled by 1/sqrt(128)*log2e.
// T1 XCD swizzle kept. 2-barrier K-loop kept (m99/m100: dbuf regresses).
// ---------------------------------------------------------------------------
#define BK 32

__global__ __launch_bounds__(256) void k_gemm_qkv(
    const uint16_t* __restrict__ A,
    const uint16_t* __restrict__ WqT,
    const uint16_t* __restrict__ WkT,
    const uint16_t* __restrict__ WvT,
    const float* __restrict__ CS,
    const float* __restrict__ SN,
    uint16_t* __restrict__ Q,
    uint16_t* __restrict__ Kb,
    uint16_t* __restrict__ Vt)
{
    __shared__ uint16_t Als[128 * BK];
    __shared__ uint16_t Bls[128 * BK];

    int bid = blockIdx.x + blockIdx.y * 36;          // 0..575
    int rid = (bid & 7) * 72 + (bid >> 3);           // XCD-chunked remap
    int nt = rid % 36;
    int m0 = (rid / 36) * 128;

    const uint16_t* Bt;
    if (nt < 28)      Bt = WqT + (size_t)nt * 128 * 3584;
    else if (nt < 32) Bt = WkT + (size_t)(nt - 28) * 128 * 3584;
    else              Bt = WvT + (size_t)(nt - 32) * 128 * 3584;

    int tid = threadIdx.x;
    int w = tid >> 6, lane = tid & 63, quad = lane >> 4, l15 = lane & 15;
    int wm = (w >> 1) * 64;
    int wn2 = (w & 1) * 32;            // column remap base

    int lrow = lane >> 2;
    int lcol = (lane & 3) * 8;

    const uint16_t* aS = A  + (size_t)(m0 + w * 32 + lrow) * 3584 + lcol;
    const uint16_t* bS = Bt + (size_t)(w * 32 + lrow) * 3584 + lcol;
    uint16_t* aD0 = &Als[(w * 32) * BK];
    uint16_t* aD1 = &Als[(w * 32 + 16) * BK];
    uint16_t* bD0 = &Bls[(w * 32) * BK];
    uint16_t* bD1 = &Bls[(w * 32 + 16) * BK];

    f32x4 acc[4][4] = {};

    for (int k0 = 0; k0 < 3584; k0 += BK) {
        __syncthreads();
        gload_lds16(aS + k0, aD0);
        gload_lds16(aS + k0 + (size_t)16 * 3584, aD1);
        gload_lds16(bS + k0, bD0);
        gload_lds16(bS + k0 + (size_t)16 * 3584, bD1);
        __syncthreads();

        bf16x8 af[4], bfr[4];
#pragma unroll
        for (int i = 0; i < 4; ++i)
            af[i] = *reinterpret_cast<const bf16x8*>(&Als[(wm + i * 16 + l15) * BK + quad * 8]);
#pragma unroll
        for (int j = 0; j < 4; ++j) {
            int br = wn2 + (j & 1) * 16 + (j >> 1) * 64;   // remapped column group
            bfr[j] = *reinterpret_cast<const bf16x8*>(&Bls[(br + l15) * BK + quad * 8]);
        }
#pragma unroll
        for (int i = 0; i < 4; ++i)
#pragma unroll
            for (int j = 0; j < 4; ++j)
                acc[i][j] = __builtin_amdgcn_mfma_f32_16x16x32_bf16(af[i], bfr[j], acc[i][j], 0, 0, 0);
    }

    if (nt < 32) {
        // -------- Q / K with fused RoPE (r8's unified branch) --------------
        uint16_t* dst   = (nt < 28) ? Q : Kb;
        int dstStride   = (nt < 28) ? 3584 : 512;
        int colBase     = (nt < 28) ? nt * 128 : (nt - 28) * 128;
        float osc = (nt < 28) ? (0.08838834764831845f * 1.4426950408889634f) : 1.0f;
#pragma unroll
        for (int i = 0; i < 4; ++i)
#pragma unroll
            for (int r = 0; r < 4; ++r) {
                int grow = m0 + wm + i * 16 + quad * 4 + r;
                const float* csr = CS + (size_t)grow * 64;
                const float* snr = SN + (size_t)grow * 64;
#pragma unroll
                for (int jp = 0; jp < 2; ++jp) {
                    int d64 = wn2 + jp * 16 + l15;
                    float cs = csr[d64];
                    float sn = snr[d64];
                    float x1 = acc[i][jp][r];              // col d64
                    float x2 = acc[i][jp + 2][r];          // col d64+64
                    dst[(size_t)grow * dstStride + colBase + d64]      = f2bf((x1 * cs - x2 * sn) * osc);
                    dst[(size_t)grow * dstStride + colBase + d64 + 64] = f2bf((x2 * cs + x1 * sn) * osc);
                }
            }
    } else {
        // -------- V: d-major Vt[d][s], packed 8B (r8's branch) -------------
        int vBase = (nt - 32) * 128;
#pragma unroll
        for (int i = 0; i < 4; ++i) {
            int grow0 = m0 + wm + i * 16 + quad * 4;
#pragma unroll
            for (int j = 0; j < 4; ++j) {
                int c = wn2 + (j & 1) * 16 + (j >> 1) * 64 + l15;
                bf16x4 pk;
#pragma unroll
                for (int r = 0; r < 4; ++r) pk[r] = (__bf16)acc[i][j][r];
                *reinterpret_cast<bf16x4*>(&Vt[(size_t)(vBase + c) * 2048 + grow0]) = pk;
            }
        }
    }
}

__global__ __launch_bounds__(256) void k_gemm_o(
    const uint16_t* __restrict__ A,
    const uint16_t* __restrict__ WoT,
    float* __restrict__ out)
{
    __shared__ uint16_t Als[128 * BK];
    __shared__ uint16_t Bls[128 * BK];

    int bid = blockIdx.x + blockIdx.y * 28;          // 0..447
    int rid = (bid & 7) * 56 + (bid >> 3);           // XCD-chunked remap
    int nt = rid % 28;
    int m0 = (rid / 28) * 128;
    const uint16_t* Bt = WoT + (size_t)nt * 128 * 3584;

    int tid = threadIdx.x;
    int w = tid >> 6, lane = tid & 63, quad = lane >> 4, l15 = lane & 15;
    int wm = (w >> 1) * 64, wn = (w & 1) * 64;

    int lrow = lane >> 2;
    int lcol = (lane & 3) * 8;

    const uint16_t* aS = A  + (size_t)(m0 + w * 32 + lrow) * 3584 + lcol;
    const uint16_t* bS = Bt + (size_t)(w * 32 + lrow) * 3584 + lcol;
    uint16_t* aD0 = &Als[(w * 32) * BK];
    uint16_t* aD1 = &Als[(w * 32 + 16) * BK];
    uint16_t* bD0 = &Bls[(w * 32) * BK];
    uint16_t* bD1 = &Bls[(w * 32 + 16) * BK];

    f32x4 acc[4][4] = {};

    for (int k0 = 0; k0 < 3584; k0 += BK) {
        __syncthreads();
        gload_lds16(aS + k0, aD0);
        gload_lds16(aS + k0 + (size_t)16 * 3584, aD1);
        gload_lds16(bS + k0, bD0);
        gload_lds16(bS + k0 + (size_t)16 * 3584, bD1);
        __syncthreads();

        bf16x8 af[4], bfr[4];
#pragma unroll
        for (int i = 0; i < 4; ++i)
            af[i] = *reinterpret_cast<const bf16x8*>(&Als[(wm + i * 16 + l15) * BK + quad * 8]);
#pragma unroll
        for (int j = 0; j < 4; ++j)
            bfr[j] = *reinterpret_cast<const bf16x8*>(&Bls[(wn + j * 16 + l15) * BK + quad * 8]);
#pragma unroll
        for (int i = 0; i < 4; ++i)
#pragma unroll
            for (int j = 0; j < 4; ++j)
                acc[i][j] = __builtin_amdgcn_mfma_f32_16x16x32_bf16(af[i], bfr[j], acc[i][j], 0, 0, 0);
    }

#pragma unroll
    for (int i = 0; i < 4; ++i)
#pragma unroll
        for (int r = 0; r < 4; ++r) {
            int grow = m0 + wm + i * 16 + quad * 4 + r;
#pragma unroll
            for (int j = 0; j < 4; ++j) {
                int gcol = nt * 128 + wn + j * 16 + l15;
                out[(size_t)grow * 3584 + gcol] = acc[i][j][r];
            }
        }
}

// ---------------------------------------------------------------------------
// Flash attention, split-K within block, swapped QK^T. K/V read from
// fragment-major layouts: every fragment load = uniform_base + lane*16B
// (coalesced 4 lines/instr vs 16-line gather -- confirmed ~-35us in r10).
// Block = 4 waves over the SAME 32 q rows; wave w owns key-tiles {w, w+4,..}.
// No barriers in main loop; bf16 AccS staging + per-wave weighted combine.
// T13 defer-rescale. Unchanged from r12 (passed).
// ---------------------------------------------------------------------------
#define FPLD 40

__global__ __launch_bounds__(256, 2) void k_flash(
    const uint16_t* __restrict__ Q,    // 2048x3584 (roped, *1/sqrt(d)*log2e)
    const uint16_t* __restrict__ Kf,   // frag-major, 4 x 262144
    const uint16_t* __restrict__ Vf,   // frag-major, 4 x 262144
    uint16_t* __restrict__ O)          // 2048x3584
{
    __shared__ uint16_t Pls[4][32 * FPLD];
    __shared__ uint16_t AccS[4][32 * 128];
    __shared__ float    Ml[4][32][2];

    int h  = blockIdx.x;               // 0..27
    int qb = 63 - (int)blockIdx.y;     // heavy first
    int kvh = h / 7;
    int tid = threadIdx.x;
    int w = tid >> 6, lane = tid & 63, quad = lane >> 4, l15 = lane & 15;
    int q0 = qb * 32;

    const uint16_t* Kfh = Kf + (size_t)kvh * 262144;
    const uint16_t* Vfh = Vf + (size_t)kvh * 262144;
    int lo8 = lane * 8;
    __bf16* Pw = reinterpret_cast<__bf16*>(&Pls[w][0]);

    // Q fragments: 32 rows (2 x 16). B-operand of the swapped mfma.
    bf16x8 qf[2][4];
#pragma unroll
    for (int s = 0; s < 2; ++s) {
        const uint16_t* qp = Q + (size_t)(q0 + s * 16 + l15) * 3584 + h * 128 + quad * 8;
#pragma unroll
        for (int c = 0; c < 4; ++c)
            qf[s][c] = *reinterpret_cast<const bf16x8*>(qp + c * 32);
    }

    f32x4 acc[2][8] = {};
    float m_i[2], l_i[2];
    m_i[0] = m_i[1] = -1e30f;
    l_i[0] = l_i[1] = 0.f;

    int tmax = qb;                     // tiles 0..qb (32 keys each)
    bf16x8 kf[8];
    int t = w;
    if (t <= tmax) {                   // prefetch first owned K tile (coalesced)
#pragma unroll
        for (int nt = 0; nt < 2; ++nt)
#pragma unroll
            for (int c = 0; c < 4; ++c)
                kf[nt * 4 + c] = *reinterpret_cast<const bf16x8*>(
                    Kfh + ((size_t)(t * 2 + nt) * 4 + c) * 512 + lo8);
    }

    for (; t <= tmax; t += 4) {
        int kb = t * 32;
        // V frags issued now, consumed after softmax (coalesced)
        bf16x8 vf[8];
#pragma unroll
        for (int dt = 0; dt < 8; ++dt)
            vf[dt] = *reinterpret_cast<const bf16x8*>(
                Vfh + ((size_t)t * 8 + dt) * 512 + lo8);

        // QK^T swapped: sc[s][nt][r] = S[key=kb+nt*16+quad*4+r][q=q0+s*16+l15]
        f32x4 sc[2][2] = {};
#pragma unroll
        for (int nt = 0; nt < 2; ++nt)
#pragma unroll
            for (int c = 0; c < 4; ++c) {
                sc[0][nt] = __builtin_amdgcn_mfma_f32_16x16x32_bf16(kf[nt * 4 + c], qf[0][c], sc[0][nt], 0, 0, 0);
                sc[1][nt] = __builtin_amdgcn_mfma_f32_16x16x32_bf16(kf[nt * 4 + c], qf[1][c], sc[1][nt], 0, 0, 0);
            }

        // prefetch next owned K tile (hidden under softmax + PV)
        int tn = t + 4;
        if (tn <= tmax) {
#pragma unroll
            for (int nt = 0; nt < 2; ++nt)
#pragma unroll
                for (int c = 0; c < 4; ++c)
                    kf[nt * 4 + c] = *reinterpret_cast<const bf16x8*>(
                        Kfh + ((size_t)(tn * 2 + nt) * 4 + c) * 512 + lo8);
        }

        // causal mask (only possible on the last tile: kb+31 > q0)
        if (kb + 31 > q0) {
#pragma unroll
            for (int s = 0; s < 2; ++s) {
                int row = q0 + s * 16 + l15;
#pragma unroll
                for (int nt = 0; nt < 2; ++nt) {
                    int keyb = kb + nt * 16 + quad * 4;
#pragma unroll
                    for (int r = 0; r < 4; ++r)
                        if (keyb + r > row) sc[s][nt][r] = -1e30f;
                }
            }
        }

        // online softmax: lane owns one q-row per s
#pragma unroll
        for (int s = 0; s < 2; ++s) {
            float mx = fmaxf(fmaxf(fmaxf(sc[s][0][0], sc[s][0][1]), fmaxf(sc[s][0][2], sc[s][0][3])),
                             fmaxf(fmaxf(sc[s][1][0], sc[s][1][1]), fmaxf(sc[s][1][2], sc[s][1][3])));
            mx = fmaxf(mx, __shfl_xor(mx, 16));
            mx = fmaxf(mx, __shfl_xor(mx, 32));
            bool nd = mx > m_i[s] + 11.5f;       // T13 defer-rescale
            float mn = nd ? mx : m_i[s];
            float alf = __builtin_amdgcn_exp2f(m_i[s] - mn);
            m_i[s] = mn;

            float rs = 0.f;
#pragma unroll
            for (int nt = 0; nt < 2; ++nt)
#pragma unroll
                for (int r = 0; r < 4; ++r) {
                    float p = __builtin_amdgcn_exp2f(sc[s][nt][r] - mn);
                    sc[s][nt][r] = p;
                    rs += p;
                }
            rs += __shfl_xor(rs, 16);
            rs += __shfl_xor(rs, 32);
            l_i[s] = l_i[s] * alf + rs;

            if (__any(nd)) {           // rare: rescale acc rows (q=quad*4+r)
                f32x4 alfr;
#pragma unroll
                for (int r = 0; r < 4; ++r)
                    alfr[r] = __shfl(alf, quad * 4 + r);
#pragma unroll
                for (int dt = 0; dt < 8; ++dt)
                    acc[s][dt] *= alfr;
            }

            // packed P-store: row q=s*16+l15, keys nt*16+quad*4..+3 (8B each)
#pragma unroll
            for (int nt = 0; nt < 2; ++nt) {
                bf16x4 pk;
#pragma unroll
                for (int r = 0; r < 4; ++r) pk[r] = (__bf16)sc[s][nt][r];
                *reinterpret_cast<bf16x4*>(&Pw[(s * 16 + l15) * FPLD + nt * 16 + quad * 4]) = pk;
            }
        }

        // PV: 32 q x 128 d over 32 keys (wave-private LDS, in-wave ordering)
        bf16x8 pf0 = *reinterpret_cast<const bf16x8*>(&Pw[l15 * FPLD + quad * 8]);
        bf16x8 pf1 = *reinterpret_cast<const bf16x8*>(&Pw[(16 + l15) * FPLD + quad * 8]);
#pragma unroll
        for (int dt = 0; dt < 8; ++dt) {
            acc[0][dt] = __builtin_amdgcn_mfma_f32_16x16x32_bf16(pf0, vf[dt], acc[0][dt], 0, 0, 0);
            acc[1][dt] = __builtin_amdgcn_mfma_f32_16x16x32_bf16(pf1, vf[dt], acc[1][dt], 0, 0, 0);
        }
    }

    // ---- write partials and combine across the 4 waves ----
    {
        __bf16* As = reinterpret_cast<__bf16*>(&AccS[w][0]);
#pragma unroll
        for (int s = 0; s < 2; ++s)
#pragma unroll
            for (int dt = 0; dt < 8; ++dt)
#pragma unroll
                for (int r = 0; r < 4; ++r)
                    As[(s * 16 + quad * 4 + r) * 128 + dt * 16 + l15] = (__bf16)acc[s][dt][r];
    }
    if (lane < 16) {                   // quad 0 lanes hold full stats for q=l15
        Ml[w][lane][0]      = m_i[0];
        Ml[w][lane][1]      = l_i[0];
        Ml[w][16 + lane][0] = m_i[1];
        Ml[w][16 + lane][1] = l_i[1];
    }
    __syncthreads();

    // combine: wave w handles rows w*8..w*8+7; lane -> (row, 16-col chunk)
    {
        int rowl = w * 8 + (lane >> 3);
        int c16 = (lane & 7) * 16;
        float m0 = Ml[0][rowl][0], m1 = Ml[1][rowl][0], m2 = Ml[2][rowl][0], m3 = Ml[3][rowl][0];
        float M = fmaxf(fmaxf(m0, m1), fmaxf(m2, m3));
        float s0 = __builtin_amdgcn_exp2f(m0 - M);
        float s1 = __builtin_amdgcn_exp2f(m1 - M);
        float s2 = __builtin_amdgcn_exp2f(m2 - M);
        float s3 = __builtin_amdgcn_exp2f(m3 - M);
        float lt = Ml[0][rowl][1] * s0 + Ml[1][rowl][1] * s1 +
                   Ml[2][rowl][1] * s2 + Ml[3][rowl][1] * s3;
        float inv = __builtin_amdgcn_rcpf(lt);
        float sw[4] = {s0, s1, s2, s3};

        float o[16];
#pragma unroll
        for (int j = 0; j < 16; ++j) o[j] = 0.f;
#pragma unroll
        for (int sl = 0; sl < 4; ++sl) {
            const uint16_t* src = &AccS[sl][rowl * 128 + c16];
            float ssc = sw[sl];
#pragma unroll
            for (int j = 0; j < 16; ++j)
                o[j] += bf2f(src[j]) * ssc;
        }
        uint16_t ob[16];
#pragma unroll
        for (int j = 0; j < 16; ++j) ob[j] = f2bf(o[j] * inv);
        uint16_t* op = O + (size_t)(q0 + rowl) * 3584 + h * 128 + c16;
        *reinterpret_cast<uint4*>(op)     = *reinterpret_cast<uint4*>(&ob[0]);
        *reinterpret_cast<uint4*>(op + 8) = *reinterpret_cast<uint4*>(&ob[8]);
    }
}

// ---------------------------------------------------------------------------
extern "C" void kernel_launch(void* const* d_in, const int* in_sizes, int n_in,
                              void* d_out, int out_size, void* d_ws, size_t ws_size,
                              hipStream_t stream) {
    const float* hidden = (const float*)d_in[0];
    const int*   pos    = (const int*)d_in[1];
    const float* Wq     = (const float*)d_in[2];
    const float* Wk     = (const float*)d_in[3];
    const float* Wv     = (const float*)d_in[4];
    const float* Wo     = (const float*)d_in[5];
    float* out = (float*)d_out;

    char* ws = (char*)d_ws;
    size_t o = 0;
    uint16_t* WqT = (uint16_t*)(ws + o); o += (size_t)3584 * 3584 * 2;
    uint16_t* WkT = (uint16_t*)(ws + o); o += (size_t)512  * 3584 * 2;
    uint16_t* WvT = (uint16_t*)(ws + o); o += (size_t)512  * 3584 * 2;
    uint16_t* WoT = (uint16_t*)(ws + o); o += (size_t)3584 * 3584 * 2;
    uint16_t* Xb  = (uint16_t*)(ws + o); o += (size_t)2048 * 3584 * 2;  // aliased as At
    uint16_t* Qb  = (uint16_t*)(ws + o); o += (size_t)2048 * 3584 * 2;
    uint16_t* Kb  = (uint16_t*)(ws + o); o += (size_t)2048 * 512  * 2;  // row-major K
    uint16_t* Kf  = (uint16_t*)(ws + o); o += (size_t)2048 * 512  * 2;  // frag-major K
    uint16_t* Vt  = (uint16_t*)(ws + o); o += (size_t)2048 * 512  * 2;  // d-major V
    uint16_t* Vf  = (uint16_t*)(ws + o); o += (size_t)2048 * 512  * 2;  // frag-major V
    float*    CSt = (float*)(ws + o);    o += (size_t)2048 * 64 * 4;
    float*    SNt = (float*)(ws + o);    o += (size_t)2048 * 64 * 4;
    uint16_t* At  = Xb;

    k_tobf16<<<dim3(7168), 256, 0, stream>>>(hidden, Xb);
    k_transpose_w<<<dim3(112, 112), 256, 0, stream>>>(Wq, WqT, 3584, 3584);
    k_transpose_w<<<dim3(16, 112),  256, 0, stream>>>(Wk, WkT, 3584, 512);
    k_transpose_w<<<dim3(16, 112),  256, 0, stream>>>(Wv, WvT, 3584, 512);
    k_transpose_w<<<dim3(112, 112), 256, 0, stream>>>(Wo, WoT, 3584, 3584);
    k_trig<<<dim3(512), 256, 0, stream>>>(pos, CSt, SNt);

    // QKV GEMM with r8's epilogue (row-major K, d-major V) + repack bridges
    k_gemm_qkv<<<dim3(36, 16), 256, 0, stream>>>(Xb, WqT, WkT, WvT, CSt, SNt, Qb, Kb, Vt);
    k_repack_k<<<dim3(512), 256, 0, stream>>>(Kb, Kf);
    k_repack_v<<<dim3(512), 256, 0, stream>>>(Vt, Vf);
    k_flash<<<dim3(28, 64), 256, 0, stream>>>(Qb, Kf, Vf, At);
    k_gemm_o<<<dim3(28, 16), 256, 0, stream>>>(At, WoT, out);
}

// Round 14
// 413.791 us; speedup vs baseline: 1.1548x; 1.0139x over previous
//
#include <hip/hip_runtime.h>
#include <cstdint>
#include <cstddef>

typedef __bf16 bf16x8 __attribute__((ext_vector_type(8)));
typedef __bf16 bf16x4 __attribute__((ext_vector_type(4)));
typedef float f32x4 __attribute__((ext_vector_type(4)));

__device__ __forceinline__ uint16_t f2bf(float f) {
    union { float f; uint32_t u; } v; v.f = f;
    uint32_t r = (v.u + 0x7fffu + ((v.u >> 16) & 1u)) >> 16;
    return (uint16_t)r;
}
__device__ __forceinline__ float bf2f(uint16_t h) {
    union { uint32_t u; float f; } v; v.u = ((uint32_t)h) << 16;
    return v.f;
}

// async 16B/lane global->LDS (wave-uniform LDS base; HW scatters lane i at +16i)
__device__ __forceinline__ void gload_lds16(const void* g, void* l) {
    __builtin_amdgcn_global_load_lds(
        (__attribute__((address_space(1))) void*)g,
        (__attribute__((address_space(3))) void*)l, 16, 0, 0);
}

// ---------------------------------------------------------------------------
// hidden fp32 -> bf16
// ---------------------------------------------------------------------------
__global__ __launch_bounds__(256) void k_tobf16(const float* __restrict__ X,
                                                uint16_t* __restrict__ Y) {
    int i = (blockIdx.x * 256 + threadIdx.x) * 4;
    f32x4 v = *reinterpret_cast<const f32x4*>(X + i);
    uint2 o;
    o.x = (uint32_t)f2bf(v[0]) | ((uint32_t)f2bf(v[1]) << 16);
    o.y = (uint32_t)f2bf(v[2]) | ((uint32_t)f2bf(v[3]) << 16);
    *reinterpret_cast<uint2*>(Y + i) = o;
}

// ---------------------------------------------------------------------------
// Weight transpose + convert: W (R x C, fp32) -> Wt (C x R, bf16)
// ---------------------------------------------------------------------------
__global__ __launch_bounds__(256) void k_transpose_w(const float* __restrict__ W,
                                                     uint16_t* __restrict__ Wt,
                                                     int R, int C) {
    __shared__ uint16_t tile[32][33];
    int c0 = blockIdx.x * 32;
    int r0 = blockIdx.y * 32;
    int t = threadIdx.x;
    int tc = t & 31, tr = t >> 5;
#pragma unroll
    for (int i = 0; i < 4; ++i) {
        int r = tr * 4 + i;
        tile[r][tc] = f2bf(W[(size_t)(r0 + r) * C + c0 + tc]);
    }
    __syncthreads();
#pragma unroll
    for (int i = 0; i < 4; ++i) {
        int c = tr * 4 + i;
        Wt[(size_t)(c0 + c) * R + r0 + tc] = tile[tc][c];
    }
}

// ---------------------------------------------------------------------------
// RoPE trig tables: CS/SN[s*64 + d]. Transcendentals ONLY here (r7 lesson:
// cosf/sinf inside the GEMM -> 64-VGPR call cap -> acc spills -> 10x).
// ---------------------------------------------------------------------------
__global__ __launch_bounds__(256) void k_trig(const int* __restrict__ pos_ids,
                                              float* __restrict__ CS,
                                              float* __restrict__ SN) {
    int idx = blockIdx.x * 256 + threadIdx.x;   // 131072
    int d = idx & 63;
    int s = idx >> 6;
    float pos = (float)pos_ids[s];
    float ang = pos * exp2f((float)d * (-19.931568569324174f / 64.0f));
    CS[idx] = cosf(ang);
    SN[idx] = sinf(ang);
}

// ---------------------------------------------------------------------------
// Fused repack (K + V): one launch instead of two.
// First 131072 threads: row-major roped K (2048x512) -> frag-major Kf.
// Next 131072 threads: d-major Vt (512x2048) -> frag-major Vf.
// Both verified in r12/r13. ~6MB moved total.
// ---------------------------------------------------------------------------
__global__ __launch_bounds__(256) void k_repack(const uint16_t* __restrict__ Kb,
                                                uint16_t* __restrict__ Kf,
                                                const uint16_t* __restrict__ Vt,
                                                uint16_t* __restrict__ Vf) {
    int lin = blockIdx.x * 256 + threadIdx.x;      // 262144
    if (lin < 131072) {
        int l15  = lin & 15;
        int quad = (lin >> 4) & 3;
        int c    = (lin >> 6) & 3;
        int nt   = (lin >> 8) & 1;
        int t    = (lin >> 9) & 63;
        int kvh  = lin >> 15;
        int tok = t * 32 + nt * 16 + l15;
        const uint16_t* src = Kb + (size_t)tok * 512 + kvh * 128 + c * 32 + quad * 8;
        uint16_t* dst = Kf + (size_t)kvh * 262144 +
                        ((size_t)(t * 2 + nt) * 4 + c) * 512 + quad * 128 + l15 * 8;
        *reinterpret_cast<uint4*>(dst) = *reinterpret_cast<const uint4*>(src);
    } else {
        int v = lin - 131072;
        int oct = v & 255;                         // tok0 = oct*8
        int d   = (v >> 8) & 127;
        int kvh = v >> 15;
        int t     = oct >> 2;
        int quad2 = oct & 3;
        int dt    = d >> 4;
        int l152  = d & 15;
        const uint16_t* src = Vt + ((size_t)kvh * 128 + d) * 2048 + (size_t)oct * 8;
        uint16_t* dst = Vf + (size_t)kvh * 262144 +
                        ((size_t)t * 8 + dt) * 512 + quad2 * 128 + l152 * 8;
        *reinterpret_cast<uint4*>(dst) = *reinterpret_cast<const uint4*>(src);
    }
}

// ---------------------------------------------------------------------------
// m97-style GEMM with FUSED RoPE + LDS chunk-swizzle (G4/T2 via rule #21:
// linear gload_lds dest + swizzled SOURCE + swizzled READ).
// Conflict math: fragment reads stride 64B -> 16 lanes on banks {0,16} =
// 8-way conflict (measured 8.26M cyc/dispatch). Swizzle chunk' =
// chunk ^ ((row>>1)&3): lanes spread over 8 half x slot combos x2 = 2-way
// (free, m136). Staging coalescing preserved (permutation within 64B row).
// All fragment-read rows are =0 mod 16, so read slot = quad ^ ((l15>>1)&3).
// r8 unified epilogue kept (r13-verified: 160->105us vs 3-way epilogue).
// ---------------------------------------------------------------------------
#define BK 32

__global__ __launch_bounds__(256) void k_gemm_qkv(
    const uint16_t* __restrict__ A,
    const uint16_t* __restrict__ WqT,
    const uint16_t* __restrict__ WkT,
    const uint16_t* __restrict__ WvT,
    const float* __restrict__ CS,
    const float* __restrict__ SN,
    uint16_t* __restrict__ Q,
    uint16_t* __restrict__ Kb,
    uint16_t* __restrict__ Vt)
{
    __shared__ uint16_t Als[128 * BK];
    __shared__ uint16_t Bls[128 * BK];

    int bid = blockIdx.x + blockIdx.y * 36;          // 0..575
    int rid = (bid & 7) * 72 + (bid >> 3);           // XCD-chunked remap
    int nt = rid % 36;
    int m0 = (rid / 36) * 128;

    const uint16_t* Bt;
    if (nt < 28)      Bt = WqT + (size_t)nt * 128 * 3584;
    else if (nt < 32) Bt = WkT + (size_t)(nt - 28) * 128 * 3584;
    else              Bt = WvT + (size_t)(nt - 32) * 128 * 3584;

    int tid = threadIdx.x;
    int w = tid >> 6, lane = tid & 63, quad = lane >> 4, l15 = lane & 15;
    int wm = (w >> 1) * 64;
    int wn2 = (w & 1) * 32;            // column remap base

    int lrow = lane >> 2;
    int lcol = (((lane & 3) ^ ((lrow >> 1) & 3))) * 8;   // swizzled source chunk
    int rsl = (quad ^ ((l15 >> 1) & 3)) * 8;             // swizzled read slot

    const uint16_t* aS = A  + (size_t)(m0 + w * 32 + lrow) * 3584 + lcol;
    const uint16_t* bS = Bt + (size_t)(w * 32 + lrow) * 3584 + lcol;
    uint16_t* aD0 = &Als[(w * 32) * BK];
    uint16_t* aD1 = &Als[(w * 32 + 16) * BK];
    uint16_t* bD0 = &Bls[(w * 32) * BK];
    uint16_t* bD1 = &Bls[(w * 32 + 16) * BK];

    f32x4 acc[4][4] = {};

    for (int k0 = 0; k0 < 3584; k0 += BK) {
        __syncthreads();
        gload_lds16(aS + k0, aD0);
        gload_lds16(aS + k0 + (size_t)16 * 3584, aD1);
        gload_lds16(bS + k0, bD0);
        gload_lds16(bS + k0 + (size_t)16 * 3584, bD1);
        __syncthreads();

        bf16x8 af[4], bfr[4];
#pragma unroll
        for (int i = 0; i < 4; ++i)
            af[i] = *reinterpret_cast<const bf16x8*>(&Als[(wm + i * 16 + l15) * BK + rsl]);
#pragma unroll
        for (int j = 0; j < 4; ++j) {
            int br = wn2 + (j & 1) * 16 + (j >> 1) * 64;   // remapped column group
            bfr[j] = *reinterpret_cast<const bf16x8*>(&Bls[(br + l15) * BK + rsl]);
        }
#pragma unroll
        for (int i = 0; i < 4; ++i)
#pragma unroll
            for (int j = 0; j < 4; ++j)
                acc[i][j] = __builtin_amdgcn_mfma_f32_16x16x32_bf16(af[i], bfr[j], acc[i][j], 0, 0, 0);
    }

    if (nt < 32) {
        // -------- Q / K with fused RoPE (r8's unified branch) --------------
        uint16_t* dst   = (nt < 28) ? Q : Kb;
        int dstStride   = (nt < 28) ? 3584 : 512;
        int colBase     = (nt < 28) ? nt * 128 : (nt - 28) * 128;
        float osc = (nt < 28) ? (0.08838834764831845f * 1.4426950408889634f) : 1.0f;
#pragma unroll
        for (int i = 0; i < 4; ++i)
#pragma unroll
            for (int r = 0; r < 4; ++r) {
                int grow = m0 + wm + i * 16 + quad * 4 + r;
                const float* csr = CS + (size_t)grow * 64;
                const float* snr = SN + (size_t)grow * 64;
#pragma unroll
                for (int jp = 0; jp < 2; ++jp) {
                    int d64 = wn2 + jp * 16 + l15;
                    float cs = csr[d64];
                    float sn = snr[d64];
                    float x1 = acc[i][jp][r];              // col d64
                    float x2 = acc[i][jp + 2][r];          // col d64+64
                    dst[(size_t)grow * dstStride + colBase + d64]      = f2bf((x1 * cs - x2 * sn) * osc);
                    dst[(size_t)grow * dstStride + colBase + d64 + 64] = f2bf((x2 * cs + x1 * sn) * osc);
                }
            }
    } else {
        // -------- V: d-major Vt[d][s], packed 8B (r8's branch) -------------
        int vBase = (nt - 32) * 128;
#pragma unroll
        for (int i = 0; i < 4; ++i) {
            int grow0 = m0 + wm + i * 16 + quad * 4;
#pragma unroll
            for (int j = 0; j < 4; ++j) {
                int c = wn2 + (j & 1) * 16 + (j >> 1) * 64 + l15;
                bf16x4 pk;
#pragma unroll
                for (int r = 0; r < 4; ++r) pk[r] = (__bf16)acc[i][j][r];
                *reinterpret_cast<bf16x4*>(&Vt[(size_t)(vBase + c) * 2048 + grow0]) = pk;
            }
        }
    }
}

__global__ __launch_bounds__(256) void k_gemm_o(
    const uint16_t* __restrict__ A,
    const uint16_t* __restrict__ WoT,
    float* __restrict__ out)
{
    __shared__ uint16_t Als[128 * BK];
    __shared__ uint16_t Bls[128 * BK];

    int bid = blockIdx.x + blockIdx.y * 28;          // 0..447
    int rid = (bid & 7) * 56 + (bid >> 3);           // XCD-chunked remap
    int nt = rid % 28;
    int m0 = (rid / 28) * 128;
    const uint16_t* Bt = WoT + (size_t)nt * 128 * 3584;

    int tid = threadIdx.x;
    int w = tid >> 6, lane = tid & 63, quad = lane >> 4, l15 = lane & 15;
    int wm = (w >> 1) * 64, wn = (w & 1) * 64;

    int lrow = lane >> 2;
    int lcol = (((lane & 3) ^ ((lrow >> 1) & 3))) * 8;   // swizzled source chunk
    int rsl = (quad ^ ((l15 >> 1) & 3)) * 8;             // swizzled read slot

    const uint16_t* aS = A  + (size_t)(m0 + w * 32 + lrow) * 3584 + lcol;
    const uint16_t* bS = Bt + (size_t)(w * 32 + lrow) * 3584 + lcol;
    uint16_t* aD0 = &Als[(w * 32) * BK];
    uint16_t* aD1 = &Als[(w * 32 + 16) * BK];
    uint16_t* bD0 = &Bls[(w * 32) * BK];
    uint16_t* bD1 = &Bls[(w * 32 + 16) * BK];

    f32x4 acc[4][4] = {};

    for (int k0 = 0; k0 < 3584; k0 += BK) {
        __syncthreads();
        gload_lds16(aS + k0, aD0);
        gload_lds16(aS + k0 + (size_t)16 * 3584, aD1);
        gload_lds16(bS + k0, bD0);
        gload_lds16(bS + k0 + (size_t)16 * 3584, bD1);
        __syncthreads();

        bf16x8 af[4], bfr[4];
#pragma unroll
        for (int i = 0; i < 4; ++i)
            af[i] = *reinterpret_cast<const bf16x8*>(&Als[(wm + i * 16 + l15) * BK + rsl]);
#pragma unroll
        for (int j = 0; j < 4; ++j)
            bfr[j] = *reinterpret_cast<const bf16x8*>(&Bls[(wn + j * 16 + l15) * BK + rsl]);
#pragma unroll
        for (int i = 0; i < 4; ++i)
#pragma unroll
            for (int j = 0; j < 4; ++j)
                acc[i][j] = __builtin_amdgcn_mfma_f32_16x16x32_bf16(af[i], bfr[j], acc[i][j], 0, 0, 0);
    }

#pragma unroll
    for (int i = 0; i < 4; ++i)
#pragma unroll
        for (int r = 0; r < 4; ++r) {
            int grow = m0 + wm + i * 16 + quad * 4 + r;
#pragma unroll
            for (int j = 0; j < 4; ++j) {
                int gcol = nt * 128 + wn + j * 16 + l15;
                out[(size_t)grow * 3584 + gcol] = acc[i][j][r];
            }
        }
}

// ---------------------------------------------------------------------------
// Flash attention, split-K within block, swapped QK^T. K/V read from
// fragment-major layouts: every fragment load = uniform_base + lane*16B
// (coalesced 4 lines/instr vs 16-line gather -- confirmed ~-35us in r10).
// Block = 4 waves over the SAME 32 q rows; wave w owns key-tiles {w, w+4,..}.
// No barriers in main loop; bf16 AccS staging + per-wave weighted combine.
// T13 defer-rescale. Unchanged from r13 (passed, <105us).
// ---------------------------------------------------------------------------
#define FPLD 40

__global__ __launch_bounds__(256, 2) void k_flash(
    const uint16_t* __restrict__ Q,    // 2048x3584 (roped, *1/sqrt(d)*log2e)
    const uint16_t* __restrict__ Kf,   // frag-major, 4 x 262144
    const uint16_t* __restrict__ Vf,   // frag-major, 4 x 262144
    uint16_t* __restrict__ O)          // 2048x3584
{
    __shared__ uint16_t Pls[4][32 * FPLD];
    __shared__ uint16_t AccS[4][32 * 128];
    __shared__ float    Ml[4][32][2];

    int h  = blockIdx.x;               // 0..27
    int qb = 63 - (int)blockIdx.y;     // heavy first
    int kvh = h / 7;
    int tid = threadIdx.x;
    int w = tid >> 6, lane = tid & 63, quad = lane >> 4, l15 = lane & 15;
    int q0 = qb * 32;

    const uint16_t* Kfh = Kf + (size_t)kvh * 262144;
    const uint16_t* Vfh = Vf + (size_t)kvh * 262144;
    int lo8 = lane * 8;
    __bf16* Pw = reinterpret_cast<__bf16*>(&Pls[w][0]);

    // Q fragments: 32 rows (2 x 16). B-operand of the swapped mfma.
    bf16x8 qf[2][4];
#pragma unroll
    for (int s = 0; s < 2; ++s) {
        const uint16_t* qp = Q + (size_t)(q0 + s * 16 + l15) * 3584 + h * 128 + quad * 8;
#pragma unroll
        for (int c = 0; c < 4; ++c)
            qf[s][c] = *reinterpret_cast<const bf16x8*>(qp + c * 32);
    }

    f32x4 acc[2][8] = {};
    float m_i[2], l_i[2];
    m_i[0] = m_i[1] = -1e30f;
    l_i[0] = l_i[1] = 0.f;

    int tmax = qb;                     // tiles 0..qb (32 keys each)
    bf16x8 kf[8];
    int t = w;
    if (t <= tmax) {                   // prefetch first owned K tile (coalesced)
#pragma unroll
        for (int nt = 0; nt < 2; ++nt)
#pragma unroll
            for (int c = 0; c < 4; ++c)
                kf[nt * 4 + c] = *reinterpret_cast<const bf16x8*>(
                    Kfh + ((size_t)(t * 2 + nt) * 4 + c) * 512 + lo8);
    }

    for (; t <= tmax; t += 4) {
        int kb = t * 32;
        // V frags issued now, consumed after softmax (coalesced)
        bf16x8 vf[8];
#pragma unroll
        for (int dt = 0; dt < 8; ++dt)
            vf[dt] = *reinterpret_cast<const bf16x8*>(
                Vfh + ((size_t)t * 8 + dt) * 512 + lo8);

        // QK^T swapped: sc[s][nt][r] = S[key=kb+nt*16+quad*4+r][q=q0+s*16+l15]
        f32x4 sc[2][2] = {};
#pragma unroll
        for (int nt = 0; nt < 2; ++nt)
#pragma unroll
            for (int c = 0; c < 4; ++c) {
                sc[0][nt] = __builtin_amdgcn_mfma_f32_16x16x32_bf16(kf[nt * 4 + c], qf[0][c], sc[0][nt], 0, 0, 0);
                sc[1][nt] = __builtin_amdgcn_mfma_f32_16x16x32_bf16(kf[nt * 4 + c], qf[1][c], sc[1][nt], 0, 0, 0);
            }

        // prefetch next owned K tile (hidden under softmax + PV)
        int tn = t + 4;
        if (tn <= tmax) {
#pragma unroll
            for (int nt = 0; nt < 2; ++nt)
#pragma unroll
                for (int c = 0; c < 4; ++c)
                    kf[nt * 4 + c] = *reinterpret_cast<const bf16x8*>(
                        Kfh + ((size_t)(tn * 2 + nt) * 4 + c) * 512 + lo8);
        }

        // causal mask (only possible on the last tile: kb+31 > q0)
        if (kb + 31 > q0) {
#pragma unroll
            for (int s = 0; s < 2; ++s) {
                int row = q0 + s * 16 + l15;
#pragma unroll
                for (int nt = 0; nt < 2; ++nt) {
                    int keyb = kb + nt * 16 + quad * 4;
#pragma unroll
                    for (int r = 0; r < 4; ++r)
                        if (keyb + r > row) sc[s][nt][r] = -1e30f;
                }
            }
        }

        // online softmax: lane owns one q-row per s
#pragma unroll
        for (int s = 0; s < 2; ++s) {
            float mx = fmaxf(fmaxf(fmaxf(sc[s][0][0], sc[s][0][1]), fmaxf(sc[s][0][2], sc[s][0][3])),
                             fmaxf(fmaxf(sc[s][1][0], sc[s][1][1]), fmaxf(sc[s][1][2], sc[s][1][3])));
            mx = fmaxf(mx, __shfl_xor(mx, 16));
            mx = fmaxf(mx, __shfl_xor(mx, 32));
            bool nd = mx > m_i[s] + 11.5f;       // T13 defer-rescale
            float mn = nd ? mx : m_i[s];
            float alf = __builtin_amdgcn_exp2f(m_i[s] - mn);
            m_i[s] = mn;

            float rs = 0.f;
#pragma unroll
            for (int nt = 0; nt < 2; ++nt)
#pragma unroll
                for (int r = 0; r < 4; ++r) {
                    float p = __builtin_amdgcn_exp2f(sc[s][nt][r] - mn);
                    sc[s][nt][r] = p;
                    rs += p;
                }
            rs += __shfl_xor(rs, 16);
            rs += __shfl_xor(rs, 32);
            l_i[s] = l_i[s] * alf + rs;

            if (__any(nd)) {           // rare: rescale acc rows (q=quad*4+r)
                f32x4 alfr;
#pragma unroll
                for (int r = 0; r < 4; ++r)
                    alfr[r] = __shfl(alf, quad * 4 + r);
#pragma unroll
                for (int dt = 0; dt < 8; ++dt)
                    acc[s][dt] *= alfr;
            }

            // packed P-store: row q=s*16+l15, keys nt*16+quad*4..+3 (8B each)
#pragma unroll
            for (int nt = 0; nt < 2; ++nt) {
                bf16x4 pk;
#pragma unroll
                for (int r = 0; r < 4; ++r) pk[r] = (__bf16)sc[s][nt][r];
                *reinterpret_cast<bf16x4*>(&Pw[(s * 16 + l15) * FPLD + nt * 16 + quad * 4]) = pk;
            }
        }

        // PV: 32 q x 128 d over 32 keys (wave-private LDS, in-wave ordering)
        bf16x8 pf0 = *reinterpret_cast<const bf16x8*>(&Pw[l15 * FPLD + quad * 8]);
        bf16x8 pf1 = *reinterpret_cast<const bf16x8*>(&Pw[(16 + l15) * FPLD + quad * 8]);
#pragma unroll
        for (int dt = 0; dt < 8; ++dt) {
            acc[0][dt] = __builtin_amdgcn_mfma_f32_16x16x32_bf16(pf0, vf[dt], acc[0][dt], 0, 0, 0);
            acc[1][dt] = __builtin_amdgcn_mfma_f32_16x16x32_bf16(pf1, vf[dt], acc[1][dt], 0, 0, 0);
        }
    }

    // ---- write partials and combine across the 4 waves ----
    {
        __bf16* As = reinterpret_cast<__bf16*>(&AccS[w][0]);
#pragma unroll
        for (int s = 0; s < 2; ++s)
#pragma unroll
            for (int dt = 0; dt < 8; ++dt)
#pragma unroll
                for (int r = 0; r < 4; ++r)
                    As[(s * 16 + quad * 4 + r) * 128 + dt * 16 + l15] = (__bf16)acc[s][dt][r];
    }
    if (lane < 16) {                   // quad 0 lanes hold full stats for q=l15
        Ml[w][lane][0]      = m_i[0];
        Ml[w][lane][1]      = l_i[0];
        Ml[w][16 + lane][0] = m_i[1];
        Ml[w][16 + lane][1] = l_i[1];
    }
    __syncthreads();

    // combine: wave w handles rows w*8..w*8+7; lane -> (row, 16-col chunk)
    {
        int rowl = w * 8 + (lane >> 3);
        int c16 = (lane & 7) * 16;
        float m0 = Ml[0][rowl][0], m1 = Ml[1][rowl][0], m2 = Ml[2][rowl][0], m3 = Ml[3][rowl][0];
        float M = fmaxf(fmaxf(m0, m1), fmaxf(m2, m3));
        float s0 = __builtin_amdgcn_exp2f(m0 - M);
        float s1 = __builtin_amdgcn_exp2f(m1 - M);
        float s2 = __builtin_amdgcn_exp2f(m2 - M);
        float s3 = __builtin_amdgcn_exp2f(m3 - M);
        float lt = Ml[0][rowl][1] * s0 + Ml[1][rowl][1] * s1 +
                   Ml[2][rowl][1] * s2 + Ml[3][rowl][1] * s3;
        float inv = __builtin_amdgcn_rcpf(lt);
        float sw[4] = {s0, s1, s2, s3};

        float o[16];
#pragma unroll
        for (int j = 0; j < 16; ++j) o[j] = 0.f;
#pragma unroll
        for (int sl = 0; sl < 4; ++sl) {
            const uint16_t* src = &AccS[sl][rowl * 128 + c16];
            float ssc = sw[sl];
#pragma unroll
            for (int j = 0; j < 16; ++j)
                o[j] += bf2f(src[j]) * ssc;
        }
        uint16_t ob[16];
#pragma unroll
        for (int j = 0; j < 16; ++j) ob[j] = f2bf(o[j] * inv);
        uint16_t* op = O + (size_t)(q0 + rowl) * 3584 + h * 128 + c16;
        *reinterpret_cast<uint4*>(op)     = *reinterpret_cast<uint4*>(&ob[0]);
        *reinterpret_cast<uint4*>(op + 8) = *reinterpret_cast<uint4*>(&ob[8]);
    }
}

// ---------------------------------------------------------------------------
extern "C" void kernel_launch(void* const* d_in, const int* in_sizes, int n_in,
                              void* d_out, int out_size, void* d_ws, size_t ws_size,
                              hipStream_t stream) {
    const float* hidden = (const float*)d_in[0];
    const int*   pos    = (const int*)d_in[1];
    const float* Wq     = (const float*)d_in[2];
    const float* Wk     = (const float*)d_in[3];
    const float* Wv     = (const float*)d_in[4];
    const float* Wo     = (const float*)d_in[5];
    float* out = (float*)d_out;

    char* ws = (char*)d_ws;
    size_t o = 0;
    uint16_t* WqT = (uint16_t*)(ws + o); o += (size_t)3584 * 3584 * 2;
    uint16_t* WkT = (uint16_t*)(ws + o); o += (size_t)512  * 3584 * 2;
    uint16_t* WvT = (uint16_t*)(ws + o); o += (size_t)512  * 3584 * 2;
    uint16_t* WoT = (uint16_t*)(ws + o); o += (size_t)3584 * 3584 * 2;
    uint16_t* Xb  = (uint16_t*)(ws + o); o += (size_t)2048 * 3584 * 2;  // aliased as At
    uint16_t* Qb  = (uint16_t*)(ws + o); o += (size_t)2048 * 3584 * 2;
    uint16_t* Kb  = (uint16_t*)(ws + o); o += (size_t)2048 * 512  * 2;  // row-major K
    uint16_t* Kf  = (uint16_t*)(ws + o); o += (size_t)2048 * 512  * 2;  // frag-major K
    uint16_t* Vt  = (uint16_t*)(ws + o); o += (size_t)2048 * 512  * 2;  // d-major V
    uint16_t* Vf  = (uint16_t*)(ws + o); o += (size_t)2048 * 512  * 2;  // frag-major V
    float*    CSt = (float*)(ws + o);    o += (size_t)2048 * 64 * 4;
    float*    SNt = (float*)(ws + o);    o += (size_t)2048 * 64 * 4;
    uint16_t* At  = Xb;

    k_tobf16<<<dim3(7168), 256, 0, stream>>>(hidden, Xb);
    k_transpose_w<<<dim3(112, 112), 256, 0, stream>>>(Wq, WqT, 3584, 3584);
    k_transpose_w<<<dim3(16, 112),  256, 0, stream>>>(Wk, WkT, 3584, 512);
    k_transpose_w<<<dim3(16, 112),  256, 0, stream>>>(Wv, WvT, 3584, 512);
    k_transpose_w<<<dim3(112, 112), 256, 0, stream>>>(Wo, WoT, 3584, 3584);
    k_trig<<<dim3(512), 256, 0, stream>>>(pos, CSt, SNt);

    // QKV GEMM (swizzled LDS) + fused repack bridge
    k_gemm_qkv<<<dim3(36, 16), 256, 0, stream>>>(Xb, WqT, WkT, WvT, CSt, SNt, Qb, Kb, Vt);
    k_repack<<<dim3(1024), 256, 0, stream>>>(Kb, Kf, Vt, Vf);
    k_flash<<<dim3(28, 64), 256, 0, stream>>>(Qb, Kf, Vf, At);
    k_gemm_o<<<dim3(28, 16), 256, 0, stream>>>(At, WoT, out);
}